// Round 7
// baseline (361.336 us; speedup 1.0000x reference)
//
#include <hip/hip_runtime.h>
#include <hip/hip_bf16.h>

typedef __bf16 bf16x4 __attribute__((ext_vector_type(4)));
typedef __bf16 bf16x8 __attribute__((ext_vector_type(8)));
typedef float floatx4 __attribute__((ext_vector_type(4)));

#define GLD16(gp, lp) __builtin_amdgcn_global_load_lds(                      \
    (const __attribute__((address_space(1))) void*)(gp),                     \
    (__attribute__((address_space(3))) void*)(lp), 16, 0, 0)

constexpr int Mdim = 16384;   // B*S
constexpr int Ndim = 3072;    // 3*D
constexpr int Kdim = 1024;    // D

static __device__ __forceinline__ bf16x8 cvt8(floatx4 lo, floatx4 hi) {
    bf16x8 r;
#pragma unroll
    for (int e = 0; e < 4; ++e) { r[e] = (__bf16)lo[e]; r[e + 4] = (__bf16)hi[e]; }
    return r;
}

// ===========================================================================
// FAST PATH (requires ws_size >= 40 MB)
// ===========================================================================

// --- prep (fused): W_eff = W_qkv + LoRA fold -> bf16;  x fp32 -> bf16 ------
__global__ __launch_bounds__(256) void prep(
    const float* __restrict__ x,
    const float* __restrict__ Wqkv,   // 3072 x 1024
    const float* __restrict__ Waq,    // 16 x 1024
    const float* __restrict__ Wbq,    // 1024 x 16
    const float* __restrict__ Wav,    // 16 x 1024
    const float* __restrict__ Wbv,    // 1024 x 16
    __hip_bfloat16* __restrict__ Weff,
    __hip_bfloat16* __restrict__ xb)
{
    if (blockIdx.x < 3072) {
        const int idx = (blockIdx.x * 256 + threadIdx.x) * 4;  // e*1024 + d
        const int e = idx >> 10;
        const int d = idx & 1023;
        floatx4 v = *(const floatx4*)(Wqkv + idx);
        if (e < 1024) {
#pragma unroll
            for (int r = 0; r < 16; ++r) {
                const float wb = Wbq[e * 16 + r];
                floatx4 wa = *(const floatx4*)(Waq + r * 1024 + d);
#pragma unroll
                for (int q = 0; q < 4; ++q) v[q] += wb * wa[q];
            }
        } else if (e >= 2048) {
            const int e2 = e - 2048;
#pragma unroll
            for (int r = 0; r < 16; ++r) {
                const float wb = Wbv[e2 * 16 + r];
                floatx4 wa = *(const floatx4*)(Wav + r * 1024 + d);
#pragma unroll
                for (int q = 0; q < 4; ++q) v[q] += wb * wa[q];
            }
        }
        bf16x4 o;
#pragma unroll
        for (int q = 0; q < 4; ++q) o[q] = (__bf16)v[q];
        *(bf16x4*)(Weff + idx) = o;
    } else {
        const size_t idx = ((size_t)(blockIdx.x - 3072) * 256 + threadIdx.x) * 8;
        bf16x8 r = cvt8(*(const floatx4*)(x + idx), *(const floatx4*)(x + idx + 4));
        *(bf16x8*)(xb + idx) = r;
    }
}

// --- main GEMM v8: 256x256, BK=64, 8 waves, m201-faithful lockstep phases --
// Per K-tile (4 phases, one output quadrant each):
//   gate: STG(A-h1,t+1) ; vmcnt(6) ; barrier   <- tile t proven landed
//   P0: issue 12 ds_reads ; barrier ; lgkm(0)+SB0 ; prio 16xMFMA
//   P1: issue 4 reads + STG(B-h1,t+1) ; barrier ; lgkm(0)+SB0 ; prio MFMA
//   P2: issue 8 reads + STG(B-h0,t+2) ; barrier ; lgkm(0)+SB0 ; prio MFMA
//   P3: barrier ; STG(A-h0,t+2) ; prio MFMA (register-only)
// Reads are issued BEFORE the phase barrier so DS latency hides under the
// barrier wait; lgkm(0) after it (rule #18: + sched_barrier(0)). vmcnt(6)
// invariant (tile t fully landed at gate) carried over from v6 unchanged.
__global__ __launch_bounds__(512, 2) void gemm_bf16_v8(
    const __hip_bfloat16* __restrict__ A,     // M x K bf16
    const __hip_bfloat16* __restrict__ Bw,    // N x K bf16 (W_eff)
    const float* __restrict__ bias,           // N fp32
    float* __restrict__ C)                    // M x N fp32
{
    constexpr int NT = Kdim / 64;             // 16 K-tiles
    // buf b at b*65536; A half h at +h*16384; B at +32768+h*16384. 128 KiB.
    __shared__ __align__(16) char smem[131072];

    const int t    = threadIdx.x;
    const int wid  = t >> 6;
    const int lane = t & 63;
    const int wm   = wid >> 2;        // 2 wave-rows, 128 out-rows each
    const int wn   = wid & 3;         // 4 wave-cols, 64 out-cols each

    constexpr int NWG = (Mdim / 256) * (Ndim / 256);  // 768, %8==0 -> bijective
    const int bid = (blockIdx.x & 7) * (NWG >> 3) + (blockIdx.x >> 3);
    const int bx  = bid % (Ndim / 256);
    const int by  = bid / (Ndim / 256);
    const int m0  = by * 256;
    const int n0  = bx * 256;

    // staging: linear LDS dest (t*16), swizzle via pre-permuted global col.
    const int srow0 = t >> 3;                              // 0..63
    const int scb   = ((t & 7) * 16) ^ ((srow0 & 7) << 4); // swizzled col-byte
    const __hip_bfloat16* Ag = A  + (size_t)(m0 + srow0) * Kdim + (scb >> 1);
    const __hip_bfloat16* Bg = Bw + (size_t)(n0 + srow0) * Kdim + (scb >> 1);

#define STG(mat, h, kt_, b_) do {                                              \
    const __hip_bfloat16* _g = ((mat) ? Bg : Ag)                               \
        + (size_t)((h) * 128) * Kdim + (kt_) * 64;                             \
    char* _l = smem + (b_) * 65536 + (mat) * 32768 + (h) * 16384 + t * 16;     \
    GLD16(_g,                     _l);                                         \
    GLD16(_g + (size_t)64 * Kdim, _l + 8192);                                  \
} while (0)

    // frag-read geometry: row stride 128 B; frag rows ≡ fm (mod 8) always.
    const int fm  = lane & 15;
    const int fk2 = (lane >> 4) * 16;
    const int fx  = (fm & 7) << 4;
    const int cb0 = fk2 ^ fx;             // k 0..31
    const int cb1 = (64 + fk2) ^ fx;      // k 32..63

    floatx4 acc[8][4];
#pragma unroll
    for (int i = 0; i < 8; ++i)
#pragma unroll
        for (int j = 0; j < 4; ++j)
            acc[i][j] = (floatx4){0.f, 0.f, 0.f, 0.f};

#define LGKM0_SB do {                                                          \
    asm volatile("s_waitcnt lgkmcnt(0)" ::: "memory");                         \
    __builtin_amdgcn_sched_barrier(0);                                         \
} while (0)

#define MFMA_Q(mq, nq, BQ)                                                     \
    __builtin_amdgcn_s_setprio(1);                                             \
    _Pragma("unroll")                                                          \
    for (int i = 0; i < 4; ++i)                                                \
        _Pragma("unroll")                                                      \
        for (int j = 0; j < 2; ++j) {                                          \
            acc[(mq) * 4 + i][(nq) * 2 + j] =                                  \
                __builtin_amdgcn_mfma_f32_16x16x32_bf16(                       \
                    aq[i][0], BQ[j][0], acc[(mq) * 4 + i][(nq) * 2 + j], 0,0,0);\
            acc[(mq) * 4 + i][(nq) * 2 + j] =                                  \
                __builtin_amdgcn_mfma_f32_16x16x32_bf16(                       \
                    aq[i][1], BQ[j][1], acc[(mq) * 4 + i][(nq) * 2 + j], 0,0,0);\
        }                                                                      \
    __builtin_amdgcn_s_setprio(0);

    // prologue: queue = A0(0) A1(0) B0(0) B1(0) B0(1) A0(1)  [12 ops]
    STG(0, 0, 0, 0); STG(0, 1, 0, 0); STG(1, 0, 0, 0); STG(1, 1, 0, 0);
    STG(1, 0, 1, 1); STG(0, 0, 1, 1);

    bf16x8 aq[4][2], bq0[2][2], bq1[2][2];

    for (int kt = 0; kt < NT; ++kt) {
        const int b = kt & 1;
        const char* Ab = smem + b * 65536;
        const char* Bb = Ab + 32768;

        // ---- gate: tile t landed & visible ----
        if (kt + 1 < NT) {
            STG(0, 1, kt + 1, b ^ 1);                        // S0: A-h1(t+1)
            asm volatile("s_waitcnt vmcnt(6)" ::: "memory");
        } else {
            asm volatile("s_waitcnt vmcnt(0)" ::: "memory");
        }
        __builtin_amdgcn_s_barrier();

        // ---- P0: quad(0,0) ----
#pragma unroll
        for (int i = 0; i < 4; ++i) {
            const char* ar = Ab + (wm * 128 + i * 16 + fm) * 128;
            aq[i][0] = *(const bf16x8*)(ar + cb0);
            aq[i][1] = *(const bf16x8*)(ar + cb1);
        }
#pragma unroll
        for (int j = 0; j < 2; ++j) {
            const char* br = Bb + (wn * 64 + j * 16 + fm) * 128;
            bq0[j][0] = *(const bf16x8*)(br + cb0);
            bq0[j][1] = *(const bf16x8*)(br + cb1);
        }
        __builtin_amdgcn_s_barrier();
        LGKM0_SB;
        MFMA_Q(0, 0, bq0)

        // ---- P1: quad(0,1) ----
#pragma unroll
        for (int j = 0; j < 2; ++j) {
            const char* br = Bb + (wn * 64 + 32 + j * 16 + fm) * 128;
            bq1[j][0] = *(const bf16x8*)(br + cb0);
            bq1[j][1] = *(const bf16x8*)(br + cb1);
        }
        if (kt + 1 < NT) STG(1, 1, kt + 1, b ^ 1);           // S1: B-h1(t+1)
        __builtin_amdgcn_s_barrier();
        LGKM0_SB;
        MFMA_Q(0, 1, bq1)

        // ---- P2: quad(1,0) ----
#pragma unroll
        for (int i = 0; i < 4; ++i) {
            const char* ar = Ab + (wm * 128 + 64 + i * 16 + fm) * 128;
            aq[i][0] = *(const bf16x8*)(ar + cb0);
            aq[i][1] = *(const bf16x8*)(ar + cb1);
        }
        if (kt + 2 < NT) STG(1, 0, kt + 2, b);               // S2: B-h0(t+2)
        __builtin_amdgcn_s_barrier();
        LGKM0_SB;
        MFMA_Q(1, 0, bq0)

        // ---- P3: quad(1,1) ---- (register-only MFMA)
        __builtin_amdgcn_s_barrier();      // all aq reads complete -> A-h0 safe
        if (kt + 2 < NT) STG(0, 0, kt + 2, b);               // S3: A-h0(t+2)
        MFMA_Q(1, 1, bq1)
    }

    // epilogue: C/D layout col(n)=lane&15, row(m)=(lane>>4)*4 + reg
    const int cn = lane & 15;
    const int cm = (lane >> 4) * 4;
    float bv[4];
#pragma unroll
    for (int j = 0; j < 4; ++j)
        bv[j] = bias[n0 + wn * 64 + j * 16 + cn];

#pragma unroll
    for (int mi = 0; mi < 8; ++mi) {
        const int m = m0 + wm * 128 + mi * 16 + cm;
#pragma unroll
        for (int ni = 0; ni < 4; ++ni) {
            const int n = n0 + wn * 64 + ni * 16 + cn;
            const size_t base = (size_t)m * Ndim + n;
#pragma unroll
            for (int r = 0; r < 4; ++r)
                C[base + (size_t)r * Ndim] = acc[mi][ni][r] + bv[ni];
        }
    }
#undef STG
#undef MFMA_Q
#undef LGKM0_SB
}

// ===========================================================================
// FALLBACK PATH (R2, proven): used only if ws_size < 40 MB
// ===========================================================================

__global__ __launch_bounds__(256, 2) void gemm_bias_f32(
    const float* __restrict__ A, const float* __restrict__ Bw,
    const float* __restrict__ bias, float* __restrict__ C)
{
    constexpr int TK = 32;
    __shared__ __hip_bfloat16 As[128 * TK];
    __shared__ __hip_bfloat16 Bs[128 * TK];

    const int t    = threadIdx.x;
    const int wave = t >> 6;
    const int lane = t & 63;
    const int bx   = blockIdx.x % (Ndim / 128);
    const int by   = blockIdx.x / (Ndim / 128);
    const int m0   = by * 128;
    const int n0   = bx * 128;
    const int wm   = wave >> 1;
    const int wn   = wave & 1;
    const int srow = wave * 16 + (lane >> 2);
    const int scol = (lane & 3) * 8;

    const float* Ag0 = A  + (size_t)(m0 + srow) * Kdim + scol;
    const float* Ag1 = Ag0 + (size_t)64 * Kdim;
    const float* Bg0 = Bw + (size_t)(n0 + srow) * Kdim + scol;
    const float* Bg1 = Bg0 + (size_t)64 * Kdim;

    __hip_bfloat16* Al0 = &As[srow * TK + scol];
    __hip_bfloat16* Al1 = &As[(srow + 64) * TK + scol];
    __hip_bfloat16* Bl0 = &Bs[srow * TK + scol];
    __hip_bfloat16* Bl1 = &Bs[(srow + 64) * TK + scol];

    const int fm = lane & 15;
    const int fk = (lane >> 4) * 8;

    floatx4 acc[4][4];
#pragma unroll
    for (int i = 0; i < 4; ++i)
#pragma unroll
        for (int j = 0; j < 4; ++j)
            acc[i][j] = (floatx4){0.f, 0.f, 0.f, 0.f};

    for (int kt = 0; kt < Kdim; kt += TK) {
        bf16x8 a0 = cvt8(*(const floatx4*)(Ag0 + kt), *(const floatx4*)(Ag0 + kt + 4));
        bf16x8 a1 = cvt8(*(const floatx4*)(Ag1 + kt), *(const floatx4*)(Ag1 + kt + 4));
        bf16x8 b0 = cvt8(*(const floatx4*)(Bg0 + kt), *(const floatx4*)(Bg0 + kt + 4));
        bf16x8 b1 = cvt8(*(const floatx4*)(Bg1 + kt), *(const floatx4*)(Bg1 + kt + 4));
        __syncthreads();
        *(bf16x8*)Al0 = a0;
        *(bf16x8*)Al1 = a1;
        *(bf16x8*)Bl0 = b0;
        *(bf16x8*)Bl1 = b1;
        __syncthreads();

        bf16x8 af[4], bfr[4];
#pragma unroll
        for (int i = 0; i < 4; ++i) {
            af[i]  = *(const bf16x8*)&As[(wm * 64 + i * 16 + fm) * TK + fk];
            bfr[i] = *(const bf16x8*)&Bs[(wn * 64 + i * 16 + fm) * TK + fk];
        }
#pragma unroll
        for (int i = 0; i < 4; ++i)
#pragma unroll
            for (int j = 0; j < 4; ++j)
                acc[i][j] = __builtin_amdgcn_mfma_f32_16x16x32_bf16(af[i], bfr[j], acc[i][j], 0, 0, 0);
    }

    const int cn = lane & 15;
    const int cm = (lane >> 4) * 4;
    float bv[4];
#pragma unroll
    for (int j = 0; j < 4; ++j)
        bv[j] = bias[n0 + wn * 64 + j * 16 + cn];
#pragma unroll
    for (int i = 0; i < 4; ++i) {
        const int m = m0 + wm * 64 + i * 16 + cm;
#pragma unroll
        for (int j = 0; j < 4; ++j) {
            const int n = n0 + wn * 64 + j * 16 + cn;
            const size_t base = (size_t)m * Ndim + n;
#pragma unroll
            for (int r = 0; r < 4; ++r)
                C[base + (size_t)r * Ndim] = acc[i][j][r] + bv[j];
        }
    }
}

__global__ __launch_bounds__(256) void lora_rmw(
    const float* __restrict__ x,
    const float* __restrict__ Waq, const float* __restrict__ Wbq,
    const float* __restrict__ Wav, const float* __restrict__ Wbv,
    float* __restrict__ out)
{
    __shared__ float Pq[64][16];
    __shared__ float Pv[64][16];
    const int t  = threadIdx.x;
    const int m0 = blockIdx.x * 64;
    {
        const int row = t >> 2;
        const int r0  = (t & 3) * 4;
        float accq[4] = {0.f, 0.f, 0.f, 0.f};
        float accv[4] = {0.f, 0.f, 0.f, 0.f};
        const float* xr = x + (size_t)(m0 + row) * Kdim;
        for (int d = 0; d < Kdim; d += 4) {
            floatx4 xv = *(const floatx4*)(xr + d);
#pragma unroll
            for (int rr = 0; rr < 4; ++rr) {
                floatx4 wq = *(const floatx4*)(Waq + (size_t)(r0 + rr) * Kdim + d);
                floatx4 wv = *(const floatx4*)(Wav + (size_t)(r0 + rr) * Kdim + d);
#pragma unroll
                for (int e = 0; e < 4; ++e) {
                    accq[rr] += xv[e] * wq[e];
                    accv[rr] += xv[e] * wv[e];
                }
            }
        }
#pragma unroll
        for (int rr = 0; rr < 4; ++rr) {
            Pq[row][r0 + rr] = accq[rr];
            Pv[row][r0 + rr] = accv[rr];
        }
    }
    __syncthreads();
    const int col  = t * 8;
    const bool isq = col < 1024;
    const int nn0  = isq ? col : col - 1024;
    const int n    = isq ? col : col + 1024;
    const float* Wb = isq ? Wbq : Wbv;
    for (int row = 0; row < 64; ++row) {
        const float* P = isq ? Pq[row] : Pv[row];
        const size_t off = (size_t)(m0 + row) * Ndim + n;
        floatx4 o0 = *(const floatx4*)(out + off);
        floatx4 o1 = *(const floatx4*)(out + off + 4);
#pragma unroll
        for (int i = 0; i < 8; ++i) {
            floatx4 w0 = *(const floatx4*)(Wb + (size_t)(nn0 + i) * 16);
            floatx4 w1 = *(const floatx4*)(Wb + (size_t)(nn0 + i) * 16 + 4);
            floatx4 w2 = *(const floatx4*)(Wb + (size_t)(nn0 + i) * 16 + 8);
            floatx4 w3 = *(const floatx4*)(Wb + (size_t)(nn0 + i) * 16 + 12);
            float s = 0.f;
#pragma unroll
            for (int r = 0; r < 4; ++r)
                s += P[r] * w0[r] + P[r + 4] * w1[r] + P[r + 8] * w2[r] + P[r + 12] * w3[r];
            if (i < 4) o0[i] += s; else o1[i - 4] += s;
        }
        *(floatx4*)(out + off)     = o0;
        *(floatx4*)(out + off + 4) = o1;
    }
}

extern "C" void kernel_launch(void* const* d_in, const int* in_sizes, int n_in,
                              void* d_out, int out_size, void* d_ws, size_t ws_size,
                              hipStream_t stream)
{
    (void)in_sizes; (void)n_in; (void)out_size;
    const float* x    = (const float*)d_in[0];
    const float* Wqkv = (const float*)d_in[1];
    const float* bqkv = (const float*)d_in[2];
    const float* Waq  = (const float*)d_in[3];
    const float* Wbq  = (const float*)d_in[4];
    const float* Wav  = (const float*)d_in[5];
    const float* Wbv  = (const float*)d_in[6];
    float* out = (float*)d_out;

    const size_t WEFF_BYTES = (size_t)Ndim * Kdim * sizeof(__hip_bfloat16); // 6.3 MB
    const size_t XB_BYTES   = (size_t)Mdim * Kdim * sizeof(__hip_bfloat16); // 33.5 MB

    if (ws_size >= WEFF_BYTES + XB_BYTES) {
        // fast path: fold LoRA into bf16 W_eff, bf16 x, single MFMA GEMM
        __hip_bfloat16* Weff = (__hip_bfloat16*)d_ws;
        __hip_bfloat16* xb   = (__hip_bfloat16*)((char*)d_ws + WEFF_BYTES);
        prep<<<3072 + 8192, 256, 0, stream>>>(x, Wqkv, Waq, Wbq, Wav, Wbv, Weff, xb);
        gemm_bf16_v8<<<(Mdim / 256) * (Ndim / 256), 512, 0, stream>>>(xb, Weff, bqkv, out);
    } else {
        // fallback: R2 proven path (no scratch)
        gemm_bias_f32<<<(Mdim / 128) * (Ndim / 128), 256, 0, stream>>>(x, Wqkv, bqkv, out);
        lora_rmw<<<Mdim / 64, 256, 0, stream>>>(x, Waq, Wbq, Wav, Wbv, out);
    }
}

// Round 8
// 350.369 us; speedup vs baseline: 1.0313x; 1.0313x over previous
//
#include <hip/hip_runtime.h>
#include <hip/hip_bf16.h>

typedef __bf16 bf16x4 __attribute__((ext_vector_type(4)));
typedef __bf16 bf16x8 __attribute__((ext_vector_type(8)));
typedef float floatx4 __attribute__((ext_vector_type(4)));

#define GLD16(gp, lp) __builtin_amdgcn_global_load_lds(                      \
    (const __attribute__((address_space(1))) void*)(gp),                     \
    (__attribute__((address_space(3))) void*)(lp), 16, 0, 0)

constexpr int Mdim = 16384;   // B*S
constexpr int Ndim = 3072;    // 3*D
constexpr int Kdim = 1024;    // D

static __device__ __forceinline__ bf16x8 cvt8(floatx4 lo, floatx4 hi) {
    bf16x8 r;
#pragma unroll
    for (int e = 0; e < 4; ++e) { r[e] = (__bf16)lo[e]; r[e + 4] = (__bf16)hi[e]; }
    return r;
}

// ===========================================================================
// FAST PATH (requires ws_size >= 40 MB)
// ===========================================================================

// --- prep (fused): W_eff = W_qkv + LoRA fold -> bf16;  x fp32 -> bf16 ------
__global__ __launch_bounds__(256) void prep(
    const float* __restrict__ x,
    const float* __restrict__ Wqkv,   // 3072 x 1024
    const float* __restrict__ Waq,    // 16 x 1024
    const float* __restrict__ Wbq,    // 1024 x 16
    const float* __restrict__ Wav,    // 16 x 1024
    const float* __restrict__ Wbv,    // 1024 x 16
    __hip_bfloat16* __restrict__ Weff,
    __hip_bfloat16* __restrict__ xb)
{
    if (blockIdx.x < 3072) {
        const int idx = (blockIdx.x * 256 + threadIdx.x) * 4;  // e*1024 + d
        const int e = idx >> 10;
        const int d = idx & 1023;
        floatx4 v = *(const floatx4*)(Wqkv + idx);
        if (e < 1024) {
#pragma unroll
            for (int r = 0; r < 16; ++r) {
                const float wb = Wbq[e * 16 + r];
                floatx4 wa = *(const floatx4*)(Waq + r * 1024 + d);
#pragma unroll
                for (int q = 0; q < 4; ++q) v[q] += wb * wa[q];
            }
        } else if (e >= 2048) {
            const int e2 = e - 2048;
#pragma unroll
            for (int r = 0; r < 16; ++r) {
                const float wb = Wbv[e2 * 16 + r];
                floatx4 wa = *(const floatx4*)(Wav + r * 1024 + d);
#pragma unroll
                for (int q = 0; q < 4; ++q) v[q] += wb * wa[q];
            }
        }
        bf16x4 o;
#pragma unroll
        for (int q = 0; q < 4; ++q) o[q] = (__bf16)v[q];
        *(bf16x4*)(Weff + idx) = o;
    } else {
        const size_t idx = ((size_t)(blockIdx.x - 3072) * 256 + threadIdx.x) * 8;
        bf16x8 r = cvt8(*(const floatx4*)(x + idx), *(const floatx4*)(x + idx + 4));
        *(bf16x8*)(xb + idx) = r;
    }
}

// --- main GEMM v9: v8 geometry + base+imm-offset ds_reads + counted lgkm ---
// 256x256, BK=64, 8 waves, both-sides XOR swizzle (0 conflicts, verified),
// vmcnt(6) once/kt (queue-derived, unchanged), 3 barriers/kt (hazard-min):
//   gate-bar: tile-t staging proven landed & visible
//   bar b (after M01): all waves' B(t) + A-lo(t) reads done -> S2 safe
//   bar c (after M10): all waves' A(t) reads done -> S3 and next S0 safe
// New: (1) all ds_reads are ds_read_b128 base+offset:imm off 4 base ptrs
// (kills ~40 VALU addr ops/kt); (2) 16 reads issued up-front, lgkmcnt(4)
// starts quad(0,0) while bq1's 4 reads still in flight (issue groups pinned
// with sched_barrier(0) so the counted wait covers exactly the right reads).
__global__ __launch_bounds__(512, 2) void gemm_bf16_v9(
    const __hip_bfloat16* __restrict__ A,     // M x K bf16
    const __hip_bfloat16* __restrict__ Bw,    // N x K bf16 (W_eff)
    const float* __restrict__ bias,           // N fp32
    float* __restrict__ C)                    // M x N fp32
{
    constexpr int NT = Kdim / 64;             // 16 K-tiles
    // buf b at b*65536; A half h at +h*16384; B at +32768+h*16384. 128 KiB.
    __shared__ __align__(16) char smem[131072];

    const int t    = threadIdx.x;
    const int wid  = t >> 6;
    const int lane = t & 63;
    const int wm   = wid >> 2;        // 2 wave-rows, 128 out-rows each
    const int wn   = wid & 3;         // 4 wave-cols, 64 out-cols each

    constexpr int NWG = (Mdim / 256) * (Ndim / 256);  // 768, %8==0 -> bijective
    const int bid = (blockIdx.x & 7) * (NWG >> 3) + (blockIdx.x >> 3);
    const int bx  = bid % (Ndim / 256);
    const int by  = bid / (Ndim / 256);
    const int m0  = by * 256;
    const int n0  = bx * 256;

    // staging: linear LDS dest (t*16), swizzle via pre-permuted global col.
    const int srow0 = t >> 3;                              // 0..63
    const int scb   = ((t & 7) * 16) ^ ((srow0 & 7) << 4); // swizzled col-byte
    const __hip_bfloat16* Ag = A  + (size_t)(m0 + srow0) * Kdim + (scb >> 1);
    const __hip_bfloat16* Bg = Bw + (size_t)(n0 + srow0) * Kdim + (scb >> 1);

#define STG(mat, h, kt_, b_) do {                                              \
    const __hip_bfloat16* _g = ((mat) ? Bg : Ag)                               \
        + (size_t)((h) * 128) * Kdim + (kt_) * 64;                             \
    char* _l = smem + (b_) * 65536 + (mat) * 32768 + (h) * 16384 + t * 16;     \
    GLD16(_g,                     _l);                                         \
    GLD16(_g + (size_t)64 * Kdim, _l + 8192);                                  \
} while (0)

    // frag-read geometry: row stride 128 B; frag rows ≡ fm (mod 8) always.
    const int fm  = lane & 15;
    const int fk2 = (lane >> 4) * 16;
    const int fx  = (fm & 7) << 4;
    const int cb0 = fk2 ^ fx;             // k 0..31
    const int cb1 = (64 + fk2) ^ fx;      // k 32..63
    const int arow = (wm * 128 + fm) * 128;   // A row-base byte offset
    const int brow = (wn * 64 + fm) * 128;    // B row-base byte offset

    floatx4 acc[8][4];
#pragma unroll
    for (int i = 0; i < 8; ++i)
#pragma unroll
        for (int j = 0; j < 4; ++j)
            acc[i][j] = (floatx4){0.f, 0.f, 0.f, 0.f};

#define MFMA_Q(mq, nq, BQ)                                                     \
    __builtin_amdgcn_s_setprio(1);                                             \
    _Pragma("unroll")                                                          \
    for (int i = 0; i < 4; ++i)                                                \
        _Pragma("unroll")                                                      \
        for (int j = 0; j < 2; ++j) {                                          \
            acc[(mq) * 4 + i][(nq) * 2 + j] =                                  \
                __builtin_amdgcn_mfma_f32_16x16x32_bf16(                       \
                    aq[i][0], BQ[j][0], acc[(mq) * 4 + i][(nq) * 2 + j], 0,0,0);\
            acc[(mq) * 4 + i][(nq) * 2 + j] =                                  \
                __builtin_amdgcn_mfma_f32_16x16x32_bf16(                       \
                    aq[i][1], BQ[j][1], acc[(mq) * 4 + i][(nq) * 2 + j], 0,0,0);\
        }                                                                      \
    __builtin_amdgcn_s_setprio(0);

    // prologue: queue = A0(0) A1(0) B0(0) B1(0) B0(1) A0(1)  [12 instrs]
    STG(0, 0, 0, 0); STG(0, 1, 0, 0); STG(1, 0, 0, 0); STG(1, 1, 0, 0);
    STG(1, 0, 1, 1); STG(0, 0, 1, 1);

    bf16x8 aq[4][2], bq0[2][2], bq1[2][2];

    for (int kt = 0; kt < NT; ++kt) {
        const int b = kt & 1;
        const char* base = smem + b * 65536;

        // ---- gate: tile t landed (vmcnt(6) retires everything older than
        // the newest 6 instrs = {S2(t-1),S3(t-1),S0(t)}) & visible ----
        if (kt + 1 < NT) {
            STG(0, 1, kt + 1, b ^ 1);                        // S0: A-h1(t+1)
            asm volatile("s_waitcnt vmcnt(6)" ::: "memory");
        } else {
            asm volatile("s_waitcnt vmcnt(0)" ::: "memory");
        }
        __builtin_amdgcn_s_barrier();

        const char* A0 = base + arow + cb0;
        const char* A1 = base + arow + cb1;
        const char* B0 = base + 32768 + brow + cb0;
        const char* B1 = base + 32768 + brow + cb1;

        // ---- issue 12 reads (aq-lo + bq0): all base+imm-offset ----
#pragma unroll
        for (int i = 0; i < 4; ++i) {
            aq[i][0] = *(const bf16x8*)(A0 + i * 2048);
            aq[i][1] = *(const bf16x8*)(A1 + i * 2048);
        }
#pragma unroll
        for (int j = 0; j < 2; ++j) {
            bq0[j][0] = *(const bf16x8*)(B0 + j * 2048);
            bq0[j][1] = *(const bf16x8*)(B1 + j * 2048);
        }
        __builtin_amdgcn_sched_barrier(0);       // pin: first 12 before next 4
        // ---- issue 4 reads (bq1) + S1 ----
#pragma unroll
        for (int j = 0; j < 2; ++j) {
            bq1[j][0] = *(const bf16x8*)(B0 + 4096 + j * 2048);
            bq1[j][1] = *(const bf16x8*)(B1 + 4096 + j * 2048);
        }
        if (kt + 1 < NT) STG(1, 1, kt + 1, b ^ 1);           // S1: B-h1(t+1)
        asm volatile("s_waitcnt lgkmcnt(4)" ::: "memory");   // 12 oldest done
        __builtin_amdgcn_sched_barrier(0);
        MFMA_Q(0, 0, bq0)
        asm volatile("s_waitcnt lgkmcnt(0)" ::: "memory");   // bq1 done
        __builtin_amdgcn_sched_barrier(0);
        MFMA_Q(0, 1, bq1)
        __builtin_amdgcn_s_barrier();            // bar b: B(t)+A-lo(t) reads done

        // ---- aq-hi reads + S2 ----
#pragma unroll
        for (int i = 0; i < 4; ++i) {
            aq[i][0] = *(const bf16x8*)(A0 + 8192 + i * 2048);
            aq[i][1] = *(const bf16x8*)(A1 + 8192 + i * 2048);
        }
        if (kt + 2 < NT) STG(1, 0, kt + 2, b);               // S2: B-h0(t+2)
        asm volatile("s_waitcnt lgkmcnt(0)" ::: "memory");
        __builtin_amdgcn_sched_barrier(0);
        MFMA_Q(1, 0, bq0)
        __builtin_amdgcn_s_barrier();            // bar c: all A(t) reads done
        if (kt + 2 < NT) STG(0, 0, kt + 2, b);               // S3: A-h0(t+2)
        MFMA_Q(1, 1, bq1)                        // register-only
    }

    // epilogue: C/D layout col(n)=lane&15, row(m)=(lane>>4)*4 + reg
    const int cn = lane & 15;
    const int cm = (lane >> 4) * 4;
    float bv[4];
#pragma unroll
    for (int j = 0; j < 4; ++j)
        bv[j] = bias[n0 + wn * 64 + j * 16 + cn];

#pragma unroll
    for (int mi = 0; mi < 8; ++mi) {
        const int m = m0 + wm * 128 + mi * 16 + cm;
#pragma unroll
        for (int ni = 0; ni < 4; ++ni) {
            const int n = n0 + wn * 64 + ni * 16 + cn;
            const size_t base2 = (size_t)m * Ndim + n;
#pragma unroll
            for (int r = 0; r < 4; ++r)
                C[base2 + (size_t)r * Ndim] = acc[mi][ni][r] + bv[ni];
        }
    }
#undef STG
#undef MFMA_Q
}

// ===========================================================================
// FALLBACK PATH (R2, proven): used only if ws_size < 40 MB
// ===========================================================================

__global__ __launch_bounds__(256, 2) void gemm_bias_f32(
    const float* __restrict__ A, const float* __restrict__ Bw,
    const float* __restrict__ bias, float* __restrict__ C)
{
    constexpr int TK = 32;
    __shared__ __hip_bfloat16 As[128 * TK];
    __shared__ __hip_bfloat16 Bs[128 * TK];

    const int t    = threadIdx.x;
    const int wave = t >> 6;
    const int lane = t & 63;
    const int bx   = blockIdx.x % (Ndim / 128);
    const int by   = blockIdx.x / (Ndim / 128);
    const int m0   = by * 128;
    const int n0   = bx * 128;
    const int wm   = wave >> 1;
    const int wn   = wave & 1;
    const int srow = wave * 16 + (lane >> 2);
    const int scol = (lane & 3) * 8;

    const float* Ag0 = A  + (size_t)(m0 + srow) * Kdim + scol;
    const float* Ag1 = Ag0 + (size_t)64 * Kdim;
    const float* Bg0 = Bw + (size_t)(n0 + srow) * Kdim + scol;
    const float* Bg1 = Bg0 + (size_t)64 * Kdim;

    __hip_bfloat16* Al0 = &As[srow * TK + scol];
    __hip_bfloat16* Al1 = &As[(srow + 64) * TK + scol];
    __hip_bfloat16* Bl0 = &Bs[srow * TK + scol];
    __hip_bfloat16* Bl1 = &Bs[(srow + 64) * TK + scol];

    const int fm = lane & 15;
    const int fk = (lane >> 4) * 8;

    floatx4 acc[4][4];
#pragma unroll
    for (int i = 0; i < 4; ++i)
#pragma unroll
        for (int j = 0; j < 4; ++j)
            acc[i][j] = (floatx4){0.f, 0.f, 0.f, 0.f};

    for (int kt = 0; kt < Kdim; kt += TK) {
        bf16x8 a0 = cvt8(*(const floatx4*)(Ag0 + kt), *(const floatx4*)(Ag0 + kt + 4));
        bf16x8 a1 = cvt8(*(const floatx4*)(Ag1 + kt), *(const floatx4*)(Ag1 + kt + 4));
        bf16x8 b0 = cvt8(*(const floatx4*)(Bg0 + kt), *(const floatx4*)(Bg0 + kt + 4));
        bf16x8 b1 = cvt8(*(const floatx4*)(Bg1 + kt), *(const floatx4*)(Bg1 + kt + 4));
        __syncthreads();
        *(bf16x8*)Al0 = a0;
        *(bf16x8*)Al1 = a1;
        *(bf16x8*)Bl0 = b0;
        *(bf16x8*)Bl1 = b1;
        __syncthreads();

        bf16x8 af[4], bfr[4];
#pragma unroll
        for (int i = 0; i < 4; ++i) {
            af[i]  = *(const bf16x8*)&As[(wm * 64 + i * 16 + fm) * TK + fk];
            bfr[i] = *(const bf16x8*)&Bs[(wn * 64 + i * 16 + fm) * TK + fk];
        }
#pragma unroll
        for (int i = 0; i < 4; ++i)
#pragma unroll
            for (int j = 0; j < 4; ++j)
                acc[i][j] = __builtin_amdgcn_mfma_f32_16x16x32_bf16(af[i], bfr[j], acc[i][j], 0, 0, 0);
    }

    const int cn = lane & 15;
    const int cm = (lane >> 4) * 4;
    float bv[4];
#pragma unroll
    for (int j = 0; j < 4; ++j)
        bv[j] = bias[n0 + wn * 64 + j * 16 + cn];
#pragma unroll
    for (int i = 0; i < 4; ++i) {
        const int m = m0 + wm * 64 + i * 16 + cm;
#pragma unroll
        for (int j = 0; j < 4; ++j) {
            const int n = n0 + wn * 64 + j * 16 + cn;
            const size_t base = (size_t)m * Ndim + n;
#pragma unroll
            for (int r = 0; r < 4; ++r)
                C[base + (size_t)r * Ndim] = acc[i][j][r] + bv[j];
        }
    }
}

__global__ __launch_bounds__(256) void lora_rmw(
    const float* __restrict__ x,
    const float* __restrict__ Waq, const float* __restrict__ Wbq,
    const float* __restrict__ Wav, const float* __restrict__ Wbv,
    float* __restrict__ out)
{
    __shared__ float Pq[64][16];
    __shared__ float Pv[64][16];
    const int t  = threadIdx.x;
    const int m0 = blockIdx.x * 64;
    {
        const int row = t >> 2;
        const int r0  = (t & 3) * 4;
        float accq[4] = {0.f, 0.f, 0.f, 0.f};
        float accv[4] = {0.f, 0.f, 0.f, 0.f};
        const float* xr = x + (size_t)(m0 + row) * Kdim;
        for (int d = 0; d < Kdim; d += 4) {
            floatx4 xv = *(const floatx4*)(xr + d);
#pragma unroll
            for (int rr = 0; rr < 4; ++rr) {
                floatx4 wq = *(const floatx4*)(Waq + (size_t)(r0 + rr) * Kdim + d);
                floatx4 wv = *(const floatx4*)(Wav + (size_t)(r0 + rr) * Kdim + d);
#pragma unroll
                for (int e = 0; e < 4; ++e) {
                    accq[rr] += xv[e] * wq[e];
                    accv[rr] += xv[e] * wv[e];
                }
            }
        }
#pragma unroll
        for (int rr = 0; rr < 4; ++rr) {
            Pq[row][r0 + rr] = accq[rr];
            Pv[row][r0 + rr] = accv[rr];
        }
    }
    __syncthreads();
    const int col  = t * 8;
    const bool isq = col < 1024;
    const int nn0  = isq ? col : col - 1024;
    const int n    = isq ? col : col + 1024;
    const float* Wb = isq ? Wbq : Wbv;
    for (int row = 0; row < 64; ++row) {
        const float* P = isq ? Pq[row] : Pv[row];
        const size_t off = (size_t)(m0 + row) * Ndim + n;
        floatx4 o0 = *(const floatx4*)(out + off);
        floatx4 o1 = *(const floatx4*)(out + off + 4);
#pragma unroll
        for (int i = 0; i < 8; ++i) {
            floatx4 w0 = *(const floatx4*)(Wb + (size_t)(nn0 + i) * 16);
            floatx4 w1 = *(const floatx4*)(Wb + (size_t)(nn0 + i) * 16 + 4);
            floatx4 w2 = *(const floatx4*)(Wb + (size_t)(nn0 + i) * 16 + 8);
            floatx4 w3 = *(const floatx4*)(Wb + (size_t)(nn0 + i) * 16 + 12);
            float s = 0.f;
#pragma unroll
            for (int r = 0; r < 4; ++r)
                s += P[r] * w0[r] + P[r + 4] * w1[r] + P[r + 8] * w2[r] + P[r + 12] * w3[r];
            if (i < 4) o0[i] += s; else o1[i - 4] += s;
        }
        *(floatx4*)(out + off)     = o0;
        *(floatx4*)(out + off + 4) = o1;
    }
}

extern "C" void kernel_launch(void* const* d_in, const int* in_sizes, int n_in,
                              void* d_out, int out_size, void* d_ws, size_t ws_size,
                              hipStream_t stream)
{
    (void)in_sizes; (void)n_in; (void)out_size;
    const float* x    = (const float*)d_in[0];
    const float* Wqkv = (const float*)d_in[1];
    const float* bqkv = (const float*)d_in[2];
    const float* Waq  = (const float*)d_in[3];
    const float* Wbq  = (const float*)d_in[4];
    const float* Wav  = (const float*)d_in[5];
    const float* Wbv  = (const float*)d_in[6];
    float* out = (float*)d_out;

    const size_t WEFF_BYTES = (size_t)Ndim * Kdim * sizeof(__hip_bfloat16); // 6.3 MB
    const size_t XB_BYTES   = (size_t)Mdim * Kdim * sizeof(__hip_bfloat16); // 33.5 MB

    if (ws_size >= WEFF_BYTES + XB_BYTES) {
        // fast path: fold LoRA into bf16 W_eff, bf16 x, single MFMA GEMM
        __hip_bfloat16* Weff = (__hip_bfloat16*)d_ws;
        __hip_bfloat16* xb   = (__hip_bfloat16*)((char*)d_ws + WEFF_BYTES);
        prep<<<3072 + 8192, 256, 0, stream>>>(x, Wqkv, Waq, Wbq, Wav, Wbv, Weff, xb);
        gemm_bf16_v9<<<(Mdim / 256) * (Ndim / 256), 512, 0, stream>>>(xb, Weff, bqkv, out);
    } else {
        // fallback: R2 proven path (no scratch)
        gemm_bias_f32<<<(Mdim / 128) * (Ndim / 128), 256, 0, stream>>>(x, Wqkv, bqkv, out);
        lora_rmw<<<Mdim / 64, 256, 0, stream>>>(x, Waq, Wbq, Wav, Wbv, out);
    }
}